// Round 6
// baseline (147.986 us; speedup 1.0000x reference)
//
#include <hip/hip_runtime.h>

// Problem constants (STEP=3 -> INTERVAL=1, W_LEN=3, N_TOK=7)
#define BB 8
#define NN 1024
#define DD 1024
#define RR 256
#define MM (BB * NN)   // 8192 rows of P
#define NTOK 7

typedef __bf16 bf16x8 __attribute__((ext_vector_type(8)));
typedef float f32x4 __attribute__((ext_vector_type(4)));

// ---------------- W f32 -> bf16 (256x1024, L2-resident afterwards) ----------------
__global__ __launch_bounds__(256) void wcvt(const float* __restrict__ W, __bf16* __restrict__ Wb) {
  const int i = (blockIdx.x * 256 + threadIdx.x) * 4;
  float4 v = *reinterpret_cast<const float4*>(W + i);
  union { __bf16 b[4]; ushort4 u; } p;
  p.b[0] = (__bf16)v.x; p.b[1] = (__bf16)v.y; p.b[2] = (__bf16)v.z; p.b[3] = (__bf16)v.w;
  *reinterpret_cast<ushort4*>(Wb + i) = p.u;
}

// ---------------- Ppad[c] = sum_k pad[k] * W[c][k] (exact f32) ----------------
__global__ void pad_proj(const float* __restrict__ Wt, const float* __restrict__ pad,
                         float* __restrict__ Ppad) {
  const int c = blockIdx.x;
  const int lane = threadIdx.x;  // 64
  float s = 0.f;
  for (int k = lane; k < DD; k += 64) s += Wt[(size_t)c * DD + k] * pad[k];
#pragma unroll
  for (int off = 32; off; off >>= 1) s += __shfl_down(s, off);
  if (lane == 0) Ppad[c] = s;
}

__device__ __forceinline__ bf16x8 cvt8(const float4& lo, const float4& hi) {
  bf16x8 r;
  r[0] = (__bf16)lo.x; r[1] = (__bf16)lo.y; r[2] = (__bf16)lo.z; r[3] = (__bf16)lo.w;
  r[4] = (__bf16)hi.x; r[5] = (__bf16)hi.y; r[6] = (__bf16)hi.z; r[7] = (__bf16)hi.w;
  return r;
}

// ---------------- Fused GEMM + assemble ----------------
// 512 blocks x 256 thr (4 waves). Block: P rows [m0, m0+16). Wave w: cols [w*64, (w+1)*64).
// MFMA loop (no LDS), then stage P-tile in LDS, write out rows [n0+2, n0+16)
// (first block of batch: [0,16) incl. j=0 zeros + j=1 Ppad case). Halo rows
// {0,1,14,15} stored to global Phalo for the cleanup kernel.
__global__ __launch_bounds__(256) void gemm_fused(const float* __restrict__ X,
                                                  const __bf16* __restrict__ Wb,
                                                  const float* __restrict__ Ppad,
                                                  const float* __restrict__ mask,
                                                  const float* __restrict__ pos,
                                                  const float* __restrict__ regtok,
                                                  float* __restrict__ Phalo,
                                                  float* __restrict__ out) {
  const int tid = threadIdx.x;
  const int wave = tid >> 6;
  const int lane = tid & 63;
  const int m0 = blockIdx.x * 16;
  const int c0 = wave * 64;
  const int lr = lane & 15;   // row(A)/col(B) within fragment
  const int lg = lane >> 4;   // k-group (8 elems each)

  const float*  xb = X  + (size_t)(m0 + lr) * DD + lg * 8;
  const __bf16* wb = Wb + (size_t)(c0 + lr) * DD + lg * 8;

  f32x4 acc[4] = {};
  float4 aA[2], aB[2];
  bf16x8 bA[4], bB[4];

#define LD_A(dst, kk) do {                                          \
    dst[0] = *reinterpret_cast<const float4*>(xb + (kk));           \
    dst[1] = *reinterpret_cast<const float4*>(xb + (kk) + 4);       \
  } while (0)
#define LD_B(dst, kk) do {                                          \
    dst[0] = *reinterpret_cast<const bf16x8*>(wb + (kk));           \
    dst[1] = *reinterpret_cast<const bf16x8*>(wb + 16 * DD + (kk)); \
    dst[2] = *reinterpret_cast<const bf16x8*>(wb + 32 * DD + (kk)); \
    dst[3] = *reinterpret_cast<const bf16x8*>(wb + 48 * DD + (kk)); \
  } while (0)
#define MFMA_STEP(aS, bS) do {                                      \
    bf16x8 af = cvt8(aS[0], aS[1]);                                 \
    acc[0] = __builtin_amdgcn_mfma_f32_16x16x32_bf16(af, bS[0], acc[0], 0, 0, 0); \
    acc[1] = __builtin_amdgcn_mfma_f32_16x16x32_bf16(af, bS[1], acc[1], 0, 0, 0); \
    acc[2] = __builtin_amdgcn_mfma_f32_16x16x32_bf16(af, bS[2], acc[2], 0, 0, 0); \
    acc[3] = __builtin_amdgcn_mfma_f32_16x16x32_bf16(af, bS[3], acc[3], 0, 0, 0); \
  } while (0)

  LD_A(aA, 0); LD_B(bA, 0);
  for (int k0 = 0; k0 < DD - 64; k0 += 64) {
    LD_A(aB, k0 + 32); LD_B(bB, k0 + 32);
    MFMA_STEP(aA, bA);
    LD_A(aA, k0 + 64); LD_B(bA, k0 + 64);
    MFMA_STEP(aB, bB);
  }
  LD_A(aB, DD - 32); LD_B(bB, DD - 32);
  MFMA_STEP(aA, bA);
  MFMA_STEP(aB, bB);

#undef LD_A
#undef LD_B
#undef MFMA_STEP

  // ---- stage P tile in LDS ----
  // C/D layout (verified m89/m91): col = lane&15, row = 4*(lane>>4) + reg
  __shared__ float Pt[16][260];  // stride 260: acc-write is 2-way max (free per m136)
#pragma unroll
  for (int ni = 0; ni < 4; ++ni)
#pragma unroll
    for (int r = 0; r < 4; ++r)
      Pt[lg * 4 + r][c0 + ni * 16 + lr] = acc[ni][r];
  __syncthreads();

  const int c4 = (tid & 63) * 4;

  // ---- halo rows {0,1,14,15} -> global ----
  {
    const int hr = tid >> 6;
    const int row = (hr < 2) ? hr : hr + 12;
    float4 v = *reinterpret_cast<const float4*>(&Pt[row][c4]);
    *reinterpret_cast<float4*>(&Phalo[(size_t)(m0 + row) * RR + c4]) = v;
  }

  // ---- assemble output rows ----
  const int b  = m0 >> 10;
  const int n0 = m0 & (NN - 1);

  float mk[NTOK];
#pragma unroll
  for (int t = 0; t < NTOK; ++t) mk[t] = mask[b * NTOK + t];
  const float4 rg = *reinterpret_cast<const float4*>(regtok + c4);
  float4 psv[NTOK];
#pragma unroll
  for (int t = 0; t < NTOK; ++t)
    psv[t] = *reinterpret_cast<const float4*>(pos + (size_t)t * RR + c4);

  const int jlo = (n0 == 0) ? 0 : n0 + 2;
  for (int j = jlo + wave; j < n0 + 16; j += 4) {
    float* outp = out + (((size_t)b * NN + j) * NTOK) * RR + c4;
    if (j == 0) {
      float4 z = make_float4(0.f, 0.f, 0.f, 0.f);
#pragma unroll
      for (int t = 0; t < NTOK; ++t)
        *reinterpret_cast<float4*>(outp + (size_t)t * RR) = z;
      continue;
    }
    float4 q[3];
#pragma unroll
    for (int w = 0; w < 3; ++w) {
      const int src = j - 2 + w;  // global row within batch; src >= n0 except Ppad case
      q[w] = (src < 0) ? *reinterpret_cast<const float4*>(Ppad + c4)
                       : *reinterpret_cast<const float4*>(&Pt[src - n0][c4]);
    }
#pragma unroll
    for (int t = 0; t < NTOK; ++t) {
      float4 v;
      if (t == 0) {
        v = rg;
      } else if (t <= 3) {
        v = q[t - 1];
      } else {
        const int w = t - 4;
        v = make_float4(q[w].x - q[1].x, q[w].y - q[1].y, q[w].z - q[1].z, q[w].w - q[1].w);
      }
      v.x = (v.x + psv[t].x) * mk[t];
      v.y = (v.y + psv[t].y) * mk[t];
      v.z = (v.z + psv[t].z) * mk[t];
      v.w = (v.w + psv[t].w) * mk[t];
      *reinterpret_cast<float4*>(outp + (size_t)t * RR) = v;
    }
  }
}

// ---------------- Cleanup: block-boundary rows j (j&15)∈{0,1}, j>=16 ----------------
// 1008 rows (126/batch x 8) x 64 threads = 252 blocks x 256 threads exactly.
// Reads halo P rows (j-2..j all in {14,15,0,1} mod 16).
#define NCLEAN_ROWS (BB * 126)   // 1008
__global__ __launch_bounds__(256) void cleanup(const float* __restrict__ Phalo,
                                               const float* __restrict__ mask,
                                               const float* __restrict__ pos,
                                               const float* __restrict__ regtok,
                                               float* __restrict__ out) {
  const int gid = blockIdx.x * 256 + threadIdx.x;
  const int rowIdx = gid >> 6;            // 0..1007
  if (rowIdx >= NCLEAN_ROWS) return;      // guard (grid sized exactly, but belt-and-braces)
  const int b  = rowIdx / 126;
  const int rr = rowIdx - b * 126;
  const int j  = 16 * ((rr >> 1) + 1) + (rr & 1);
  const int c4 = (gid & 63) * 4;

  float4 q[3];
#pragma unroll
  for (int w = 0; w < 3; ++w)
    q[w] = *reinterpret_cast<const float4*>(&Phalo[((size_t)b * NN + j - 2 + w) * RR + c4]);

  const float4 rg = *reinterpret_cast<const float4*>(regtok + c4);
  float* outp = out + (((size_t)b * NN + j) * NTOK) * RR + c4;

#pragma unroll
  for (int t = 0; t < NTOK; ++t) {
    const float4 ps = *reinterpret_cast<const float4*>(pos + (size_t)t * RR + c4);
    const float m = mask[b * NTOK + t];
    float4 v;
    if (t == 0) {
      v = rg;
    } else if (t <= 3) {
      v = q[t - 1];
    } else {
      const int w = t - 4;
      v = make_float4(q[w].x - q[1].x, q[w].y - q[1].y, q[w].z - q[1].z, q[w].w - q[1].w);
    }
    v.x = (v.x + ps.x) * m;
    v.y = (v.y + ps.y) * m;
    v.z = (v.z + ps.z) * m;
    v.w = (v.w + ps.w) * m;
    *reinterpret_cast<float4*>(outp + (size_t)t * RR) = v;
  }
}

extern "C" void kernel_launch(void* const* d_in, const int* in_sizes, int n_in,
                              void* d_out, int out_size, void* d_ws, size_t ws_size,
                              hipStream_t stream) {
  const float* x      = (const float*)d_in[0];  // (8,1024,1024)
  const float* mask   = (const float*)d_in[1];  // (8,7,1)
  const float* W      = (const float*)d_in[2];  // (256,1024)
  const float* pos    = (const float*)d_in[3];  // (1,7,256)
  const float* regtok = (const float*)d_in[4];  // (1,1,256)
  const float* pad    = (const float*)d_in[5];  // (1,1,1024)
  float* out = (float*)d_out;

  // ws layout: Phalo (8 MiB, only halo rows touched) | Wb (512 KiB) | Ppad (1 KiB)
  float*  Phalo = (float*)d_ws;
  __bf16* Wb    = (__bf16*)((char*)d_ws + (size_t)MM * RR * 4);
  float*  Ppad  = (float*)((char*)d_ws + (size_t)MM * RR * 4 + (size_t)RR * DD * 2);

  wcvt<<<RR * DD / (256 * 4), 256, 0, stream>>>(W, Wb);
  pad_proj<<<RR, 64, 0, stream>>>(W, pad, Ppad);
  gemm_fused<<<MM / 16, 256, 0, stream>>>(x, Wb, Ppad, mask, pos, regtok, Phalo, out);
  cleanup<<<NCLEAN_ROWS * 64 / 256, 256, 0, stream>>>(Phalo, mask, pos, regtok, out);
}

// Round 7
// 133.406 us; speedup vs baseline: 1.1093x; 1.1093x over previous
//
#include <hip/hip_runtime.h>

// Problem constants (STEP=3 -> INTERVAL=1, W_LEN=3, N_TOK=7)
#define BB 8
#define NN 1024
#define DD 1024
#define RR 256
#define MM (BB * NN)   // 8192 rows of P
#define NTOK 7
#define BKT 64         // K per pipeline step
#define NKT (DD / BKT) // 16 steps

typedef __bf16 bf16x8 __attribute__((ext_vector_type(8)));
typedef float f32x4 __attribute__((ext_vector_type(4)));

// ---------------- W f32 -> bf16 (256x1024, L2-resident afterwards) ----------------
__global__ __launch_bounds__(256) void wcvt(const float* __restrict__ W, __bf16* __restrict__ Wb) {
  const int i = (blockIdx.x * 256 + threadIdx.x) * 4;
  float4 v = *reinterpret_cast<const float4*>(W + i);
  union { __bf16 b[4]; ushort4 u; } p;
  p.b[0] = (__bf16)v.x; p.b[1] = (__bf16)v.y; p.b[2] = (__bf16)v.z; p.b[3] = (__bf16)v.w;
  *reinterpret_cast<ushort4*>(Wb + i) = p.u;
}

// ---------------- Ppad[c] = sum_k pad[k] * W[c][k] (exact f32) ----------------
__global__ void pad_proj(const float* __restrict__ Wt, const float* __restrict__ pad,
                         float* __restrict__ Ppad) {
  const int c = blockIdx.x;
  const int lane = threadIdx.x;  // 64
  float s = 0.f;
  for (int k = lane; k < DD; k += 64) s += Wt[(size_t)c * DD + k] * pad[k];
#pragma unroll
  for (int off = 32; off; off >>= 1) s += __shfl_down(s, off);
  if (lane == 0) Ppad[c] = s;
}

__device__ __forceinline__ bf16x8 cvt8(const float4& lo, const float4& hi) {
  bf16x8 r;
  r[0] = (__bf16)lo.x; r[1] = (__bf16)lo.y; r[2] = (__bf16)lo.z; r[3] = (__bf16)lo.w;
  r[4] = (__bf16)hi.x; r[5] = (__bf16)hi.y; r[6] = (__bf16)hi.z; r[7] = (__bf16)hi.w;
  return r;
}

// ---------------- Fused GEMM + assemble (m97-style 2-barrier LDS-DMA pipeline) ----
// 512 blocks x 256 thr (4 waves). Block: P rows [m0, m0+16), all 4 waves share the
// A tile; wave w owns cols [w*64, (w+1)*64).
// A tile (16x64 f32 = 4KB) double-buffered in LDS via global_load_lds (16B/thread/step),
// XOR-swizzled: physical granule p = logical granule g ^ (row&7), applied on BOTH the
// global source address (pre-swizzle) and the ds_read granule (rule #21).
// B read direct from L2-hot Wb. One __syncthreads per K-step.
__global__ __launch_bounds__(256) void gemm_fused(const float* __restrict__ X,
                                                  const __bf16* __restrict__ Wb,
                                                  const float* __restrict__ Ppad,
                                                  const float* __restrict__ mask,
                                                  const float* __restrict__ pos,
                                                  const float* __restrict__ regtok,
                                                  float* __restrict__ Phalo,
                                                  float* __restrict__ out) {
  const int tid = threadIdx.x;
  const int wave = tid >> 6;
  const int lane = tid & 63;
  const int m0 = blockIdx.x * 16;
  const int c0 = wave * 64;
  const int lr = lane & 15;   // A-row / B-col within fragment
  const int lg = lane >> 4;   // k-group (8 elems)

  __shared__ __align__(16) float Ab[2][16 * BKT];  // 2 x 4KB, linear for DMA
  __shared__ float Pt[16][260];

  // --- staging source (pre-swizzled): thread = physical granule p = tid ---
  const int srow = tid >> 4;                  // 0..15
  const int sgc  = (tid & 15) ^ (srow & 7);   // logical 16B-granule within row
  const float* srcbase = X + (size_t)(m0 + srow) * DD + sgc * 4;
  // wave-uniform LDS dest base (HW adds lane*16)
  float* dst0 = &Ab[0][wave * 256];
  float* dst1 = &Ab[1][wave * 256];

  // --- A-frag swizzled read granules (frag ks: k in [ks*32, ks*32+32), this lane: lg*8..+8) ---
  const int g00 = lr * 16 + lg * 2;           // ks=0, elems 0-3
  const int p00 = g00 ^ (lr & 7);
  const int p10 = (g00 + 8) ^ (lr & 7);       // ks=1 (bit3 untouched by XOR)

  // --- B pointer ---
  const __bf16* wb = Wb + (size_t)(c0 + lr) * DD + lg * 8;

  f32x4 acc[4] = {};

#define STAGE(dst, kt) \
  __builtin_amdgcn_global_load_lds( \
      (const __attribute__((address_space(1))) void*)(srcbase + (kt) * BKT), \
      (__attribute__((address_space(3))) void*)(dst), 16, 0, 0)

  STAGE(dst0, 0);
  __syncthreads();

  for (int kt = 0; kt < NKT; ++kt) {
    const int cur = kt & 1;
    if (kt < NKT - 1) {
      STAGE((cur ? dst0 : dst1), kt + 1);
    }
    // B frags for this K-step (L2-hot)
    bf16x8 bfr[4][2];
#pragma unroll
    for (int ni = 0; ni < 4; ++ni) {
#pragma unroll
      for (int ks = 0; ks < 2; ++ks)
        bfr[ni][ks] = *reinterpret_cast<const bf16x8*>(wb + (size_t)ni * 16 * DD + kt * BKT + ks * 32);
    }
    // A frags from LDS (swizzled granules)
    const float4* ab4 = reinterpret_cast<const float4*>(&Ab[cur][0]);
    float4 lo0 = ab4[p00], hi0 = ab4[p00 ^ 1];
    float4 lo1 = ab4[p10], hi1 = ab4[p10 ^ 1];
    bf16x8 af0 = cvt8(lo0, hi0);
    bf16x8 af1 = cvt8(lo1, hi1);
#pragma unroll
    for (int ni = 0; ni < 4; ++ni) {
      acc[ni] = __builtin_amdgcn_mfma_f32_16x16x32_bf16(af0, bfr[ni][0], acc[ni], 0, 0, 0);
      acc[ni] = __builtin_amdgcn_mfma_f32_16x16x32_bf16(af1, bfr[ni][1], acc[ni], 0, 0, 0);
    }
    __syncthreads();  // drains DMA (vmcnt) + LDS reads, releases buffers
  }
#undef STAGE

  // ---- stage P tile in LDS ----
  // C/D layout (verified m89/m91): col = lane&15, row = 4*(lane>>4) + reg
#pragma unroll
  for (int ni = 0; ni < 4; ++ni)
#pragma unroll
    for (int r = 0; r < 4; ++r)
      Pt[lg * 4 + r][c0 + ni * 16 + lr] = acc[ni][r];
  __syncthreads();

  const int c4 = (tid & 63) * 4;

  // ---- halo rows {0,1,14,15} -> global ----
  {
    const int hr = tid >> 6;
    const int row = (hr < 2) ? hr : hr + 12;
    float4 v = *reinterpret_cast<const float4*>(&Pt[row][c4]);
    *reinterpret_cast<float4*>(&Phalo[(size_t)(m0 + row) * RR + c4]) = v;
  }

  // ---- assemble output rows ----
  const int b  = m0 >> 10;
  const int n0 = m0 & (NN - 1);

  float mk[NTOK];
#pragma unroll
  for (int t = 0; t < NTOK; ++t) mk[t] = mask[b * NTOK + t];
  const float4 rg = *reinterpret_cast<const float4*>(regtok + c4);
  float4 psv[NTOK];
#pragma unroll
  for (int t = 0; t < NTOK; ++t)
    psv[t] = *reinterpret_cast<const float4*>(pos + (size_t)t * RR + c4);

  const int jlo = (n0 == 0) ? 0 : n0 + 2;
  for (int j = jlo + wave; j < n0 + 16; j += 4) {
    float* outp = out + (((size_t)b * NN + j) * NTOK) * RR + c4;
    if (j == 0) {
      float4 z = make_float4(0.f, 0.f, 0.f, 0.f);
#pragma unroll
      for (int t = 0; t < NTOK; ++t)
        *reinterpret_cast<float4*>(outp + (size_t)t * RR) = z;
      continue;
    }
    float4 q[3];
#pragma unroll
    for (int w = 0; w < 3; ++w) {
      const int src = j - 2 + w;  // row within batch; >= n0 except Ppad case
      q[w] = (src < 0) ? *reinterpret_cast<const float4*>(Ppad + c4)
                       : *reinterpret_cast<const float4*>(&Pt[src - n0][c4]);
    }
#pragma unroll
    for (int t = 0; t < NTOK; ++t) {
      float4 v;
      if (t == 0) {
        v = rg;
      } else if (t <= 3) {
        v = q[t - 1];
      } else {
        const int w = t - 4;
        v = make_float4(q[w].x - q[1].x, q[w].y - q[1].y, q[w].z - q[1].z, q[w].w - q[1].w);
      }
      v.x = (v.x + psv[t].x) * mk[t];
      v.y = (v.y + psv[t].y) * mk[t];
      v.z = (v.z + psv[t].z) * mk[t];
      v.w = (v.w + psv[t].w) * mk[t];
      *reinterpret_cast<float4*>(outp + (size_t)t * RR) = v;
    }
  }
}

// ---------------- Cleanup: block-boundary rows j (j&15)∈{0,1}, j>=16 ----------------
// 1008 rows (126/batch x 8) x 64 threads = 252 blocks x 256 threads exactly.
#define NCLEAN_ROWS (BB * 126)   // 1008
__global__ __launch_bounds__(256) void cleanup(const float* __restrict__ Phalo,
                                               const float* __restrict__ mask,
                                               const float* __restrict__ pos,
                                               const float* __restrict__ regtok,
                                               float* __restrict__ out) {
  const int gid = blockIdx.x * 256 + threadIdx.x;
  const int rowIdx = gid >> 6;            // 0..1007
  if (rowIdx >= NCLEAN_ROWS) return;
  const int b  = rowIdx / 126;
  const int rr = rowIdx - b * 126;
  const int j  = 16 * ((rr >> 1) + 1) + (rr & 1);
  const int c4 = (gid & 63) * 4;

  float4 q[3];
#pragma unroll
  for (int w = 0; w < 3; ++w)
    q[w] = *reinterpret_cast<const float4*>(&Phalo[((size_t)b * NN + j - 2 + w) * RR + c4]);

  const float4 rg = *reinterpret_cast<const float4*>(regtok + c4);
  float* outp = out + (((size_t)b * NN + j) * NTOK) * RR + c4;

#pragma unroll
  for (int t = 0; t < NTOK; ++t) {
    const float4 ps = *reinterpret_cast<const float4*>(pos + (size_t)t * RR + c4);
    const float m = mask[b * NTOK + t];
    float4 v;
    if (t == 0) {
      v = rg;
    } else if (t <= 3) {
      v = q[t - 1];
    } else {
      const int w = t - 4;
      v = make_float4(q[w].x - q[1].x, q[w].y - q[1].y, q[w].z - q[1].z, q[w].w - q[1].w);
    }
    v.x = (v.x + ps.x) * m;
    v.y = (v.y + ps.y) * m;
    v.z = (v.z + ps.z) * m;
    v.w = (v.w + ps.w) * m;
    *reinterpret_cast<float4*>(outp + (size_t)t * RR) = v;
  }
}

extern "C" void kernel_launch(void* const* d_in, const int* in_sizes, int n_in,
                              void* d_out, int out_size, void* d_ws, size_t ws_size,
                              hipStream_t stream) {
  const float* x      = (const float*)d_in[0];  // (8,1024,1024)
  const float* mask   = (const float*)d_in[1];  // (8,7,1)
  const float* W      = (const float*)d_in[2];  // (256,1024)
  const float* pos    = (const float*)d_in[3];  // (1,7,256)
  const float* regtok = (const float*)d_in[4];  // (1,1,256)
  const float* pad    = (const float*)d_in[5];  // (1,1,1024)
  float* out = (float*)d_out;

  // ws layout: Phalo (8 MiB, only halo rows touched) | Wb (512 KiB) | Ppad (1 KiB)
  float*  Phalo = (float*)d_ws;
  __bf16* Wb    = (__bf16*)((char*)d_ws + (size_t)MM * RR * 4);
  float*  Ppad  = (float*)((char*)d_ws + (size_t)MM * RR * 4 + (size_t)RR * DD * 2);

  wcvt<<<RR * DD / (256 * 4), 256, 0, stream>>>(W, Wb);
  pad_proj<<<RR, 64, 0, stream>>>(W, pad, Ppad);
  gemm_fused<<<MM / 16, 256, 0, stream>>>(x, Wb, Ppad, mask, pos, regtok, Phalo, out);
  cleanup<<<NCLEAN_ROWS * 64 / 256, 256, 0, stream>>>(Phalo, mask, pos, regtok, out);
}

// Round 9
// 124.298 us; speedup vs baseline: 1.1906x; 1.0733x over previous
//
#include <hip/hip_runtime.h>

// Problem constants (STEP=3 -> INTERVAL=1, W_LEN=3, N_TOK=7)
#define BB 8
#define NN 1024
#define DD 1024
#define RR 256
#define MM (BB * NN)   // 8192 rows of P
#define NTOK 7
#define BKT 64         // K per pipeline step
#define NKT (DD / BKT) // 16 steps

typedef __bf16 bf16x8 __attribute__((ext_vector_type(8)));
typedef float f32x4 __attribute__((ext_vector_type(4)));

__device__ __forceinline__ bf16x8 cvt8(const float4& lo, const float4& hi) {
  bf16x8 r;
  r[0] = (__bf16)lo.x; r[1] = (__bf16)lo.y; r[2] = (__bf16)lo.z; r[3] = (__bf16)lo.w;
  r[4] = (__bf16)hi.x; r[5] = (__bf16)hi.y; r[6] = (__bf16)hi.z; r[7] = (__bf16)hi.w;
  return r;
}

// ---------------- W f32 -> bf16 in MFMA-fragment-contiguous order ----------------
// Granule g = ctile*2048 + kslice*64 + lane (8 bf16 each) holds
// W[ctile*16 + (lane&15)][kslice*32 + (lane>>4)*8 + e].
// A wave's B-frag load becomes one contiguous 1KB segment (base + lane*16B).
__global__ __launch_bounds__(256) void wcvt(const float* __restrict__ W, __bf16* __restrict__ Wb) {
  const int t = blockIdx.x * 256 + threadIdx.x;   // 0..32767
  const int lane   = t & 63;
  const int kslice = (t >> 6) & 31;
  const int ctile  = t >> 11;
  const int col = ctile * 16 + (lane & 15);
  const int k0  = kslice * 32 + (lane >> 4) * 8;
  const float* src = W + (size_t)col * DD + k0;
  float4 lo = *reinterpret_cast<const float4*>(src);
  float4 hi = *reinterpret_cast<const float4*>(src + 4);
  bf16x8 v = cvt8(lo, hi);
  *reinterpret_cast<bf16x8*>(Wb + (size_t)t * 8) = v;
}

// ---------------- Ppad[c] = sum_k pad[k] * W[c][k] (exact f32) ----------------
__global__ void pad_proj(const float* __restrict__ Wt, const float* __restrict__ pad,
                         float* __restrict__ Ppad) {
  const int c = blockIdx.x;
  const int lane = threadIdx.x;  // 64
  float s = 0.f;
  for (int k = lane; k < DD; k += 64) s += Wt[(size_t)c * DD + k] * pad[k];
#pragma unroll
  for (int off = 32; off; off >>= 1) s += __shfl_down(s, off);
  if (lane == 0) Ppad[c] = s;
}

// ---------------- Fused GEMM + assemble (r7-proven 2-barrier LDS-DMA pipeline,
//                  + fragment-ordered coalesced B loads) ----
// 512 blocks x 256 thr (4 waves). Block: P rows [m0, m0+16); wave w: cols [w*64,(w+1)*64).
// A tile (16x64 f32 = 4KB) double-buffered via global_load_lds (16B/thread/step),
// XOR-swizzled (granule g at physical g^(row&7)) on BOTH global source and ds_read.
// B from fragment-ordered Wb: one contiguous 1KB load per (ni,ks), L2-hot.
__global__ __launch_bounds__(256) void gemm_fused(const float* __restrict__ X,
                                                  const __bf16* __restrict__ Wb,
                                                  const float* __restrict__ Ppad,
                                                  const float* __restrict__ mask,
                                                  const float* __restrict__ pos,
                                                  const float* __restrict__ regtok,
                                                  float* __restrict__ Phalo,
                                                  float* __restrict__ out) {
  const int tid = threadIdx.x;
  const int wave = tid >> 6;
  const int lane = tid & 63;
  const int m0 = blockIdx.x * 16;
  const int c0 = wave * 64;
  const int lr = lane & 15;   // A-row / B-col within fragment
  const int lg = lane >> 4;   // k-group (8 elems)

  __shared__ __align__(16) float Ab[2][16 * BKT];  // 2 x 4KB, linear for DMA
  __shared__ float Pt[16][260];

  // --- staging source (pre-swizzled): thread = physical granule p = tid ---
  const int srow = tid >> 4;                  // 0..15
  const int sgc  = (tid & 15) ^ (srow & 7);   // logical 16B-granule within row
  const float* srcbase = X + (size_t)(m0 + srow) * DD + sgc * 4;
  // wave-uniform LDS dest base (HW adds lane*16)
  float* dst0 = &Ab[0][wave * 256];
  float* dst1 = &Ab[1][wave * 256];

  // --- A-frag swizzled read granules ---
  const int g00 = lr * 16 + lg * 2;           // ks=0
  const int p00 = g00 ^ (lr & 7);
  const int p10 = (g00 + 8) ^ (lr & 7);       // ks=1 (bit3 untouched by XOR)

  // --- B pointer (fragment-ordered Wb; granule = (wave*4+ni)*2048 + kslice*64 + lane) ---
  const __bf16* wbf = Wb + ((size_t)(wave * 128) * 64 + lane) * 8;

  f32x4 acc[4] = {};

#define STAGE(dst, kt) \
  __builtin_amdgcn_global_load_lds( \
      (const __attribute__((address_space(1))) void*)(srcbase + (kt) * BKT), \
      (__attribute__((address_space(3))) void*)(dst), 16, 0, 0)

  STAGE(dst0, 0);
  __syncthreads();

  for (int kt = 0; kt < NKT; ++kt) {
    const int cur = kt & 1;
    if (kt < NKT - 1) {
      STAGE((cur ? dst0 : dst1), kt + 1);
    }
    // B frags for this K-step: contiguous 1KB coalesced loads (L2-hot)
    bf16x8 bfr[4][2];
#pragma unroll
    for (int ni = 0; ni < 4; ++ni) {
#pragma unroll
      for (int ks = 0; ks < 2; ++ks)
        bfr[ni][ks] = *reinterpret_cast<const bf16x8*>(
            wbf + (size_t)(ni * 32 + kt * 2 + ks) * 512);
    }
    // A frags from LDS (swizzled granules)
    const float4* ab4 = reinterpret_cast<const float4*>(&Ab[cur][0]);
    float4 lo0 = ab4[p00], hi0 = ab4[p00 ^ 1];
    float4 lo1 = ab4[p10], hi1 = ab4[p10 ^ 1];
    bf16x8 af0 = cvt8(lo0, hi0);
    bf16x8 af1 = cvt8(lo1, hi1);
#pragma unroll
    for (int ni = 0; ni < 4; ++ni) {
      acc[ni] = __builtin_amdgcn_mfma_f32_16x16x32_bf16(af0, bfr[ni][0], acc[ni], 0, 0, 0);
      acc[ni] = __builtin_amdgcn_mfma_f32_16x16x32_bf16(af1, bfr[ni][1], acc[ni], 0, 0, 0);
    }
    __syncthreads();  // drains DMA (vmcnt) + LDS reads, releases buffers
  }
#undef STAGE

  // ---- stage P tile in LDS ----
  // C/D layout (verified m89/m91): col = lane&15, row = 4*(lane>>4) + reg
#pragma unroll
  for (int ni = 0; ni < 4; ++ni)
#pragma unroll
    for (int r = 0; r < 4; ++r)
      Pt[lg * 4 + r][c0 + ni * 16 + lr] = acc[ni][r];
  __syncthreads();

  const int c4 = (tid & 63) * 4;

  // ---- halo rows {0,1,14,15} -> global ----
  {
    const int hr = tid >> 6;
    const int row = (hr < 2) ? hr : hr + 12;
    float4 v = *reinterpret_cast<const float4*>(&Pt[row][c4]);
    *reinterpret_cast<float4*>(&Phalo[(size_t)(m0 + row) * RR + c4]) = v;
  }

  // ---- assemble output rows ----
  const int b  = m0 >> 10;
  const int n0 = m0 & (NN - 1);

  float mk[NTOK];
#pragma unroll
  for (int t = 0; t < NTOK; ++t) mk[t] = mask[b * NTOK + t];
  const float4 rg = *reinterpret_cast<const float4*>(regtok + c4);
  float4 psv[NTOK];
#pragma unroll
  for (int t = 0; t < NTOK; ++t)
    psv[t] = *reinterpret_cast<const float4*>(pos + (size_t)t * RR + c4);

  const int jlo = (n0 == 0) ? 0 : n0 + 2;
  for (int j = jlo + wave; j < n0 + 16; j += 4) {
    float* outp = out + (((size_t)b * NN + j) * NTOK) * RR + c4;
    if (j == 0) {
      float4 z = make_float4(0.f, 0.f, 0.f, 0.f);
#pragma unroll
      for (int t = 0; t < NTOK; ++t)
        *reinterpret_cast<float4*>(outp + (size_t)t * RR) = z;
      continue;
    }
    float4 q[3];
#pragma unroll
    for (int w = 0; w < 3; ++w) {
      const int src = j - 2 + w;  // row within batch; >= n0 except Ppad case
      q[w] = (src < 0) ? *reinterpret_cast<const float4*>(Ppad + c4)
                       : *reinterpret_cast<const float4*>(&Pt[src - n0][c4]);
    }
#pragma unroll
    for (int t = 0; t < NTOK; ++t) {
      float4 v;
      if (t == 0) {
        v = rg;
      } else if (t <= 3) {
        v = q[t - 1];
      } else {
        const int w = t - 4;
        v = make_float4(q[w].x - q[1].x, q[w].y - q[1].y, q[w].z - q[1].z, q[w].w - q[1].w);
      }
      v.x = (v.x + psv[t].x) * mk[t];
      v.y = (v.y + psv[t].y) * mk[t];
      v.z = (v.z + psv[t].z) * mk[t];
      v.w = (v.w + psv[t].w) * mk[t];
      *reinterpret_cast<float4*>(outp + (size_t)t * RR) = v;
    }
  }
}

// ---------------- Cleanup: block-boundary rows j (j&15)∈{0,1}, j>=16 ----------------
// 1008 rows (126/batch x 8) x 64 threads = 252 blocks x 256 threads exactly.
#define NCLEAN_ROWS (BB * 126)   // 1008
__global__ __launch_bounds__(256) void cleanup(const float* __restrict__ Phalo,
                                               const float* __restrict__ mask,
                                               const float* __restrict__ pos,
                                               const float* __restrict__ regtok,
                                               float* __restrict__ out) {
  const int gid = blockIdx.x * 256 + threadIdx.x;
  const int rowIdx = gid >> 6;            // 0..1007
  if (rowIdx >= NCLEAN_ROWS) return;
  const int b  = rowIdx / 126;
  const int rr = rowIdx - b * 126;
  const int j  = 16 * ((rr >> 1) + 1) + (rr & 1);
  const int c4 = (gid & 63) * 4;

  float4 q[3];
#pragma unroll
  for (int w = 0; w < 3; ++w)
    q[w] = *reinterpret_cast<const float4*>(&Phalo[((size_t)b * NN + j - 2 + w) * RR + c4]);

  const float4 rg = *reinterpret_cast<const float4*>(regtok + c4);
  float* outp = out + (((size_t)b * NN + j) * NTOK) * RR + c4;

#pragma unroll
  for (int t = 0; t < NTOK; ++t) {
    const float4 ps = *reinterpret_cast<const float4*>(pos + (size_t)t * RR + c4);
    const float m = mask[b * NTOK + t];
    float4 v;
    if (t == 0) {
      v = rg;
    } else if (t <= 3) {
      v = q[t - 1];
    } else {
      const int w = t - 4;
      v = make_float4(q[w].x - q[1].x, q[w].y - q[1].y, q[w].z - q[1].z, q[w].w - q[1].w);
    }
    v.x = (v.x + ps.x) * m;
    v.y = (v.y + ps.y) * m;
    v.z = (v.z + ps.z) * m;
    v.w = (v.w + ps.w) * m;
    *reinterpret_cast<float4*>(outp + (size_t)t * RR) = v;
  }
}

extern "C" void kernel_launch(void* const* d_in, const int* in_sizes, int n_in,
                              void* d_out, int out_size, void* d_ws, size_t ws_size,
                              hipStream_t stream) {
  const float* x      = (const float*)d_in[0];  // (8,1024,1024)
  const float* mask   = (const float*)d_in[1];  // (8,7,1)
  const float* W      = (const float*)d_in[2];  // (256,1024)
  const float* pos    = (const float*)d_in[3];  // (1,7,256)
  const float* regtok = (const float*)d_in[4];  // (1,1,256)
  const float* pad    = (const float*)d_in[5];  // (1,1,1024)
  float* out = (float*)d_out;

  // ws layout: Phalo (8 MiB, only halo rows touched) | Wb (512 KiB) | Ppad (1 KiB)
  float*  Phalo = (float*)d_ws;
  __bf16* Wb    = (__bf16*)((char*)d_ws + (size_t)MM * RR * 4);
  float*  Ppad  = (float*)((char*)d_ws + (size_t)MM * RR * 4 + (size_t)RR * DD * 2);

  wcvt<<<RR * DD / (256 * 8), 256, 0, stream>>>(W, Wb);   // 128 blocks, frag-ordered
  pad_proj<<<RR, 64, 0, stream>>>(W, pad, Ppad);
  gemm_fused<<<MM / 16, 256, 0, stream>>>(x, Wb, Ppad, mask, pos, regtok, Phalo, out);
  cleanup<<<NCLEAN_ROWS * 64 / 256, 256, 0, stream>>>(Phalo, mask, pos, regtok, out);
}